// Round 9
// baseline (93.214 us; speedup 1.0000x reference)
//
#include <hip/hip_runtime.h>
#include <hip/hip_bf16.h>
#include <math.h>

#define B 4
#define T 8
#define NF 8192
#define C 384
#define H 12
#define TOPK 32
#define D 32
#define STOT (T + NF)          // 8200
#define R (H * T)              // 96 score rows per batch
#define KSEL 48                // selection margin (bf16 keys -> exact fp32 rescore)
#define SCALE 0.17677669529663687f

typedef unsigned int uint;
typedef unsigned short ushort;
typedef short bf16x8 __attribute__((ext_vector_type(8)));
typedef float f32x4 __attribute__((ext_vector_type(4)));

__device__ __forceinline__ ushort bf16u(float a) {
  return __builtin_bit_cast(ushort, __float2bfloat16(a));
}

// order-preserving u16 key from f32 (bf16 RNE, sign-flip encode)
__device__ __forceinline__ ushort f32_key(float s) {
  uint kb = bf16u(s);
  kb ^= (kb & 0x8000u) ? 0xFFFFu : 0x8000u;
  return (ushort)kb;
}

// ---------------------------------------------------------------------------
// Kernel 1a: q-projection. grid (T, 6 o-tiles, 2 k-halves), 256 thr.
// ---------------------------------------------------------------------------
__global__ __launch_bounds__(256) void ta_qproj_kernel(
    const float* __restrict__ x, const float* __restrict__ qs_w,
    float* __restrict__ q_part) {
  int t = blockIdx.x;
  int o0 = blockIdx.y * 64;
  int z = blockIdx.z;
  int tid = threadIdx.x;
  int o = tid & 63, ks = tid >> 6;
  __shared__ float xs[B][192];
  __shared__ float part[4][B][64];
  if (tid < 192) {
    int b = tid / 48, j4 = (tid % 48) * 4;
    *reinterpret_cast<float4*>(&xs[b][j4]) =
        *reinterpret_cast<const float4*>(x + ((size_t)b * STOT + t) * C + z * 192 + j4);
  }
  __syncthreads();
  float a0 = 0.f, a1 = 0.f, a2 = 0.f, a3 = 0.f;
  const float* w = qs_w + (size_t)t * C * C + (size_t)(z * 192 + ks * 48) * C + o0 + o;
#pragma unroll 8
  for (int c = 0; c < 48; ++c) {
    float wv = w[(size_t)c * C];
    int cj = ks * 48 + c;
    a0 += xs[0][cj] * wv;
    a1 += xs[1][cj] * wv;
    a2 += xs[2][cj] * wv;
    a3 += xs[3][cj] * wv;
  }
  part[ks][0][o] = a0; part[ks][1][o] = a1;
  part[ks][2][o] = a2; part[ks][3][o] = a3;
  __syncthreads();
  {
    int b = tid >> 6, oo = tid & 63;
    float s = part[0][b][oo] + part[1][b][oo] + part[2][b][oo] + part[3][b][oo];
    q_part[(((size_t)z * B + b) * T + t) * C + o0 + oo] = s;
  }
}

// ---------------------------------------------------------------------------
// Kernel 1b: fold k-projection. grid B*H, 384 thr (thread = c).
// ---------------------------------------------------------------------------
__global__ __launch_bounds__(384) void ta_fold_kernel(
    const float* __restrict__ q_part, const float* __restrict__ kv_w,
    float* __restrict__ qk_f32, ushort* __restrict__ qk_bf) {
  int b = blockIdx.x / H, h = blockIdx.x % H;
  int tid = threadIdx.x;
  __shared__ float kS[C][33];
  __shared__ float qh[T][D];
  if (tid < T * D) {
    int t = tid >> 5, d = tid & 31;
    qh[t][d] = q_part[((size_t)b * T + t) * C + h * D + d] +
               q_part[(((size_t)B + b) * T + t) * C + h * D + d];
  }
  for (int j = tid; j < C * 8; j += 384) {
    int c = j >> 3, d4 = (j & 7) * 4;
    float4 v = *reinterpret_cast<const float4*>(
        kv_w + (size_t)c * (2 * C) + h * D + d4);
    kS[c][d4 + 0] = v.x; kS[c][d4 + 1] = v.y;
    kS[c][d4 + 2] = v.z; kS[c][d4 + 3] = v.w;
  }
  __syncthreads();
  float acc[T] = {0.f, 0.f, 0.f, 0.f, 0.f, 0.f, 0.f, 0.f};
#pragma unroll
  for (int d = 0; d < D; ++d) {
    float kv = kS[tid][d];
#pragma unroll
    for (int t = 0; t < T; ++t) acc[t] += qh[t][d] * kv;
  }
#pragma unroll
  for (int t = 0; t < T; ++t) {
    size_t off = ((size_t)b * R + (size_t)h * T + t) * C + tid;
    float a = acc[t];
    qk_f32[off] = a;
    qk_bf[off] = bf16u(a);
  }
}

// ---------------------------------------------------------------------------
// Kernel 2: bf16 MFMA scores -> u16 sort-keys, plus d_out zeroing (overlapped
// with compute; completes before ta_selgv's scatter by stream order).
// ---------------------------------------------------------------------------
__global__ __launch_bounds__(256) void ta_scores_kernel(
    const float* __restrict__ x, const ushort* __restrict__ qk_bf,
    ushort* __restrict__ keys, float4* __restrict__ out4) {
  int b = blockIdx.y;
  int n0 = blockIdx.x * 64;
  int tid = threadIdx.x;
  int lane = tid & 63, w = tid >> 6;
  int row16 = lane & 15, kg = lane >> 4;
  __shared__ ushort fS[64][72];
  __shared__ ushort qS[96][72];
  f32x4 acc[6];
#pragma unroll
  for (int i = 0; i < 6; ++i) acc[i] = (f32x4){0.f, 0.f, 0.f, 0.f};

  // zero my slice of d_out (512 blocks x 6150 float4 = full out); these
  // stores drain under the MFMA loop below.
  {
    const int SL = (B * STOT * C / 4) / 512;  // 6150
    int zbid = blockIdx.y * gridDim.x + blockIdx.x;
    float4 z = {0.f, 0.f, 0.f, 0.f};
    float4* dst = out4 + (size_t)zbid * SL;
    for (int j = tid; j < SL; j += 256) dst[j] = z;
  }

  const float* xb = x + ((size_t)b * STOT + T + n0) * C;
  const ushort* qb = qk_bf + (size_t)b * R * C;

  int frow = tid >> 2, fcg = (tid & 3) * 8;

#pragma unroll 1
  for (int c0 = 0; c0 < C; c0 += 32) {
    {
      const float* src = xb + (size_t)frow * C + c0 + fcg;
      float4 v0 = *reinterpret_cast<const float4*>(src);
      float4 v1 = *reinterpret_cast<const float4*>(src + 4);
      uint4 p;
      p.x = (uint)bf16u(v0.x) | ((uint)bf16u(v0.y) << 16);
      p.y = (uint)bf16u(v0.z) | ((uint)bf16u(v0.w) << 16);
      p.z = (uint)bf16u(v1.x) | ((uint)bf16u(v1.y) << 16);
      p.w = (uint)bf16u(v1.z) | ((uint)bf16u(v1.w) << 16);
      *reinterpret_cast<uint4*>(&fS[frow][fcg]) = p;
    }
#pragma unroll
    for (int s = 0; s < 2; ++s) {
      int u = tid + 256 * s;
      if (u < 384) {
        int row = u >> 2, cg = (u & 3) * 8;
        uint4 v = *reinterpret_cast<const uint4*>(qb + (size_t)row * C + c0 + cg);
        *reinterpret_cast<uint4*>(&qS[row][cg]) = v;
      }
    }
    __syncthreads();
    bf16x8 bfr = *reinterpret_cast<const bf16x8*>(&fS[w * 16 + row16][kg * 8]);
#pragma unroll
    for (int i = 0; i < 6; ++i) {
      bf16x8 afr = *reinterpret_cast<const bf16x8*>(&qS[i * 16 + row16][kg * 8]);
      acc[i] = __builtin_amdgcn_mfma_f32_16x16x32_bf16(afr, bfr, acc[i], 0, 0, 0);
    }
    __syncthreads();
  }
  int n = n0 + w * 16 + row16;
#pragma unroll
  for (int i = 0; i < 6; ++i) {
    int rbase = i * 16 + kg * 4;
#pragma unroll
    for (int reg = 0; reg < 4; ++reg) {
      keys[((size_t)b * R + rbase + reg) * NF + n] = f32_key(acc[i][reg] * SCALE);
    }
  }
}

// ---------------------------------------------------------------------------
// Kernel 3: fully fused per-row tail: 2-pass radix select on u16 keys ->
// exact fp32 rescore/softmax -> gv (chunked LDS) -> scatter. One block per
// (b,h,t) row, 256 thr. Selection LDS overlaid with gv tiles via union.
// ---------------------------------------------------------------------------
__global__ __launch_bounds__(256) void ta_selgv_kernel(
    const ushort* __restrict__ keys, const float* __restrict__ x,
    const float* __restrict__ qk_f32, const float* __restrict__ kv_w,
    const float* __restrict__ ew, float* __restrict__ out) {
  int br = blockIdx.x;
  int t = br % T, h = (br / T) % H, b = br / R;
  int tid = threadIdx.x;
  int lane = tid & 63, wvi = tid >> 6;   // 4 waves

  union SM {
    struct {
      ushort su[NF];          // 16 KB
      uint histW[4][256];     // 4 KB
      float qS[C];
      int gt_list[KSEL];
      int eq_list[128];
      int il[KSEL];
      float sv[KSEL];
      int rkS[KSEL];
    } a;
    struct {
      float Fc[TOPK][100];    // 12.8 KB
      float Vc[96][36];       // 13.8 KB
    } g;
  };
  __shared__ SM sm;
  __shared__ float vS[TOPK][36];
  __shared__ float gS[TOPK][36];
  __shared__ __align__(16) float attS[D];
  __shared__ float wl[TOPK];
  __shared__ int top_il[TOPK];
  __shared__ uint sh_prefix, sh_above, cgt, ceq;
  __shared__ float smax, esum;

  // ---- stage keys + qk row ----
  {
    const uint4* src = reinterpret_cast<const uint4*>(keys + (size_t)br * NF);
    uint4* dst = reinterpret_cast<uint4*>(sm.a.su);
    for (int j = tid; j < NF / 8; j += 256) dst[j] = src[j];
  }
  for (int j = tid; j < C; j += 256) sm.a.qS[j] = qk_f32[(size_t)br * C + j];
  for (int i = tid; i < 4 * 256; i += 256) (&sm.a.histW[0][0])[i] = 0;
  if (tid == 0) { cgt = 0; ceq = 0; }
  __syncthreads();

  // ---- radix pass 1: top byte ----
  for (int i = tid; i < NF; i += 256) atomicAdd(&sm.a.histW[wvi][sm.a.su[i] >> 8], 1u);
  __syncthreads();
  if (tid < 64) {
    uint h0 = 0, h1 = 0, h2 = 0, h3 = 0;
#pragma unroll
    for (int wq = 0; wq < 4; ++wq) {
      h0 += sm.a.histW[wq][4 * lane + 0];
      h1 += sm.a.histW[wq][4 * lane + 1];
      h2 += sm.a.histW[wq][4 * lane + 2];
      h3 += sm.a.histW[wq][4 * lane + 3];
    }
    uint lsum = h0 + h1 + h2 + h3;
    uint suf = lsum;
#pragma unroll
    for (int off = 1; off < 64; off <<= 1) {
      uint o = __shfl_down(suf, off);
      if (lane + off < 64) suf += o;
    }
    uint gn3 = suf - lsum;
    uint ge3 = gn3 + h3;
    uint ge2 = ge3 + h2;
    uint ge1 = ge2 + h1;
    uint ge0 = ge1 + h0;
    const uint need = KSEL;
    if (ge0 >= need && ge1 < need) { sh_prefix = 4 * lane + 0; sh_above = ge1; }
    if (ge1 >= need && ge2 < need) { sh_prefix = 4 * lane + 1; sh_above = ge2; }
    if (ge2 >= need && ge3 < need) { sh_prefix = 4 * lane + 2; sh_above = ge3; }
    if (ge3 >= need && gn3 < need) { sh_prefix = 4 * lane + 3; sh_above = gn3; }
  }
  __syncthreads();
  uint pref1 = sh_prefix, ab1 = sh_above;
  for (int i = tid; i < 4 * 256; i += 256) (&sm.a.histW[0][0])[i] = 0;
  __syncthreads();
  // ---- radix pass 2: low byte among prefix matches ----
  for (int i = tid; i < NF; i += 256) {
    uint u = sm.a.su[i];
    if ((u >> 8) == pref1) atomicAdd(&sm.a.histW[wvi][u & 255], 1u);
  }
  __syncthreads();
  if (tid < 64) {
    uint h0 = 0, h1 = 0, h2 = 0, h3 = 0;
#pragma unroll
    for (int wq = 0; wq < 4; ++wq) {
      h0 += sm.a.histW[wq][4 * lane + 0];
      h1 += sm.a.histW[wq][4 * lane + 1];
      h2 += sm.a.histW[wq][4 * lane + 2];
      h3 += sm.a.histW[wq][4 * lane + 3];
    }
    uint lsum = h0 + h1 + h2 + h3;
    uint suf = lsum;
#pragma unroll
    for (int off = 1; off < 64; off <<= 1) {
      uint o = __shfl_down(suf, off);
      if (lane + off < 64) suf += o;
    }
    uint gn3 = suf - lsum;
    uint ge3 = gn3 + h3;
    uint ge2 = ge3 + h2;
    uint ge1 = ge2 + h1;
    uint ge0 = ge1 + h0;
    const uint need = (uint)KSEL - ab1;
    if (ge0 >= need && ge1 < need) { sh_prefix = (pref1 << 8) | (4 * lane + 0); sh_above = ab1 + ge1; }
    if (ge1 >= need && ge2 < need) { sh_prefix = (pref1 << 8) | (4 * lane + 1); sh_above = ab1 + ge2; }
    if (ge2 >= need && ge3 < need) { sh_prefix = (pref1 << 8) | (4 * lane + 2); sh_above = ab1 + ge3; }
    if (ge3 >= need && gn3 < need) { sh_prefix = (pref1 << 8) | (4 * lane + 3); sh_above = ab1 + gn3; }
  }
  __syncthreads();
  uint piv = sh_prefix, ab = sh_above;   // ab = #(key > piv) < KSEL
  for (int i = tid; i < NF; i += 256) {
    uint u = sm.a.su[i];
    if (u > piv) {
      uint s = atomicAdd(&cgt, 1u);
      sm.a.gt_list[s] = i;
    } else if (u == piv) {
      uint s = atomicAdd(&ceq, 1u);
      if (s < 128) sm.a.eq_list[s] = i;
    }
  }
  __syncthreads();
  if (tid < (int)ab) sm.a.il[tid] = sm.a.gt_list[tid];
  {
    uint ne = ceq < 128u ? ceq : 128u;
    if (tid < (int)ne) {
      int my = sm.a.eq_list[tid];
      int r2 = 0;
      for (uint e = 0; e < ne; ++e) r2 += (sm.a.eq_list[e] < my);
      if (r2 < (int)((uint)KSEL - ab)) sm.a.il[ab + r2] = my;
    }
  }
  __syncthreads();

  // ---- exact fp32 rescore: 48 cands x 8 lanes in 1.5 rounds ----
  {
    int k = tid >> 3, j = tid & 7;   // k 0..31
    const float* fp = x + ((size_t)b * STOT + T + sm.a.il[k]) * C + j;
    float s = 0.f;
#pragma unroll 8
    for (int m = 0; m < 48; ++m) s += fp[m * 8] * sm.a.qS[j + m * 8];
    s += __shfl_down(s, 4);
    s += __shfl_down(s, 2);
    s += __shfl_down(s, 1);
    if (j == 0) sm.a.sv[k] = s * SCALE;
  }
  if (tid < 128) {
    int k = 32 + (tid >> 3), j = tid & 7;  // k 32..47
    const float* fp = x + ((size_t)b * STOT + T + sm.a.il[k]) * C + j;
    float s = 0.f;
#pragma unroll 8
    for (int m = 0; m < 48; ++m) s += fp[m * 8] * sm.a.qS[j + m * 8];
    s += __shfl_down(s, 4);
    s += __shfl_down(s, 2);
    s += __shfl_down(s, 1);
    if (j == 0) sm.a.sv[k] = s * SCALE;
  }
  __syncthreads();
  if (tid < KSEL) {
    float mys = sm.a.sv[tid];
    int myn = sm.a.il[tid];
    int r = 0;
#pragma unroll
    for (int e = 0; e < KSEL; ++e) {
      float se = sm.a.sv[e];
      r += (se > mys) || (se == mys && sm.a.il[e] < myn);
    }
    sm.a.rkS[tid] = r;
    if (r == 0) smax = mys;
  }
  __syncthreads();
  {
    float e = 0.f;
    if (tid < KSEL && sm.a.rkS[tid] < TOPK) e = expf(sm.a.sv[tid] - smax);
    if (tid < 64) {
      float t2 = e;
#pragma unroll
      for (int off = 32; off; off >>= 1) t2 += __shfl_down(t2, off);
      if (tid == 0) esum = t2;
    }
    __syncthreads();
    if (tid < KSEL && sm.a.rkS[tid] < TOPK) {
      wl[sm.a.rkS[tid]] = e / esum;
      top_il[sm.a.rkS[tid]] = sm.a.il[tid];
    }
  }
  __syncthreads();  // selection LDS dead; union region reused below

  // ---- gv phase: 32 k x 8 dg, c in 4 chunks of 96 ----
  int k = tid >> 3, dg = tid & 7;
  float4 acc = {0.f, 0.f, 0.f, 0.f};
  int hc = (h * D) / 96;
#pragma unroll 1
  for (int ch = 0; ch < 4; ++ch) {
    int c0 = ch * 96;
    if (ch) __syncthreads();
#pragma unroll
    for (int s = 0; s < 3; ++s) {
      int u = tid + 256 * s;
      int kr = u / 24, c4 = (u % 24) * 4;
      *reinterpret_cast<float4*>(&sm.g.Fc[kr][c4]) =
          *reinterpret_cast<const float4*>(
              x + ((size_t)b * STOT + T + top_il[kr]) * C + c0 + c4);
    }
#pragma unroll
    for (int s = 0; s < 3; ++s) {
      int u = tid + 256 * s;
      int cr = u >> 3, d4 = (u & 7) * 4;
      *reinterpret_cast<float4*>(&sm.g.Vc[cr][d4]) =
          *reinterpret_cast<const float4*>(
              kv_w + (size_t)(c0 + cr) * (2 * C) + C + h * D + d4);
    }
    __syncthreads();
    if (ch == hc) {  // g[k][d] = wl[k] * F[k][hD+d]
      int off = h * D - c0;
      float4 f = *reinterpret_cast<const float4*>(&sm.g.Fc[k][off + 4 * dg]);
      float wk = wl[k];
      float4 g = {wk * f.x, wk * f.y, wk * f.z, wk * f.w};
      *reinterpret_cast<float4*>(&gS[k][4 * dg]) = g;
    }
#pragma unroll 4
    for (int c = 0; c < 96; c += 4) {
      float4 f4 = *reinterpret_cast<const float4*>(&sm.g.Fc[k][c]);
      float4 v0 = *reinterpret_cast<const float4*>(&sm.g.Vc[c + 0][4 * dg]);
      float4 v1 = *reinterpret_cast<const float4*>(&sm.g.Vc[c + 1][4 * dg]);
      float4 v2 = *reinterpret_cast<const float4*>(&sm.g.Vc[c + 2][4 * dg]);
      float4 v3 = *reinterpret_cast<const float4*>(&sm.g.Vc[c + 3][4 * dg]);
      acc.x += f4.x * v0.x + f4.y * v1.x + f4.z * v2.x + f4.w * v3.x;
      acc.y += f4.x * v0.y + f4.y * v1.y + f4.z * v2.y + f4.w * v3.y;
      acc.z += f4.x * v0.z + f4.y * v1.z + f4.z * v2.z + f4.w * v3.z;
      acc.w += f4.x * v0.w + f4.y * v1.w + f4.z * v2.w + f4.w * v3.w;
    }
  }
  *reinterpret_cast<float4*>(&vS[k][4 * dg]) = acc;
  __syncthreads();
  if (tid < D) {
    float a = 0.f;
#pragma unroll
    for (int kk = 0; kk < TOPK; ++kk) a += wl[kk] * vS[kk][tid];
    attS[tid] = a;
  }
  __syncthreads();

  // ---- scatter: columns o0 = tid, o1 = tid + 256 (tid < 128) ----
  float ewc0[D], ewc1[D];
  const float* ewt = ew + (size_t)t * C * C + (size_t)h * D * C;
#pragma unroll
  for (int dd = 0; dd < D; ++dd) {
    ewc0[dd] = ewt[(size_t)dd * C + tid];
    ewc1[dd] = (tid < 128) ? ewt[(size_t)dd * C + tid + 256] : 0.f;
  }
  size_t obase = (size_t)b * STOT * C;
#pragma unroll 1
  for (int kk = 0; kk < TOPK; ++kk) {
    float y0 = 0.f, y1 = 0.f;
#pragma unroll
    for (int d4 = 0; d4 < D; d4 += 4) {
      float4 g4 = *reinterpret_cast<const float4*>(&gS[kk][d4]);
      y0 += g4.x * ewc0[d4] + g4.y * ewc0[d4 + 1] +
            g4.z * ewc0[d4 + 2] + g4.w * ewc0[d4 + 3];
      y1 += g4.x * ewc1[d4] + g4.y * ewc1[d4 + 1] +
            g4.z * ewc1[d4 + 2] + g4.w * ewc1[d4 + 3];
    }
    size_t row = obase + (size_t)(T + top_il[kk]) * C;
    atomicAdd(&out[row + tid], y0);
    if (tid < 128) atomicAdd(&out[row + tid + 256], y1);
  }
  {
    float y0 = 0.f, y1 = 0.f;
#pragma unroll
    for (int d4 = 0; d4 < D; d4 += 4) {
      float4 a4 = *reinterpret_cast<const float4*>(attS + d4);
      y0 += a4.x * ewc0[d4] + a4.y * ewc0[d4 + 1] +
            a4.z * ewc0[d4 + 2] + a4.w * ewc0[d4 + 3];
      y1 += a4.x * ewc1[d4] + a4.y * ewc1[d4 + 1] +
            a4.z * ewc1[d4 + 2] + a4.w * ewc1[d4 + 3];
    }
    size_t row = obase + (size_t)t * C;
    atomicAdd(&out[row + tid], y0);
    if (tid < 128) atomicAdd(&out[row + tid + 256], y1);
  }
}

// ---------------------------------------------------------------------------
extern "C" void kernel_launch(void* const* d_in, const int* in_sizes, int n_in,
                              void* d_out, int out_size, void* d_ws, size_t ws_size,
                              hipStream_t stream) {
  const float* x = (const float*)d_in[0];
  const float* qs_w = (const float*)d_in[1];
  const float* kv_w = (const float*)d_in[2];
  const float* ew = (const float*)d_in[3];
  float* out = (float*)d_out;

  char* p = (char*)d_ws;
  float* qk_f32 = (float*)p;  p += (size_t)B * R * C * 4;        // 589824
  ushort* qk_bf = (ushort*)p; p += (size_t)B * R * C * 2;        // 294912
  ushort* keys = (ushort*)p;  p += (size_t)B * R * NF * 2;       // 6291456
  float* q_part = (float*)p;  // 2*B*T*C floats

  dim3 gq(T, C / 64, 2);
  ta_qproj_kernel<<<gq, 256, 0, stream>>>(x, qs_w, q_part);
  ta_fold_kernel<<<B * H, 384, 0, stream>>>(q_part, kv_w, qk_f32, qk_bf);
  dim3 g2(NF / 64, B);
  ta_scores_kernel<<<g2, 256, 0, stream>>>(x, qk_bf, keys, (float4*)out);
  ta_selgv_kernel<<<B * R, 256, 0, stream>>>(keys, x, qk_f32, kv_w, ew, out);
}

// Round 10
// 87.640 us; speedup vs baseline: 1.0636x; 1.0636x over previous
//
#include <hip/hip_runtime.h>
#include <hip/hip_bf16.h>
#include <math.h>

#define B 4
#define T 8
#define NF 8192
#define C 384
#define H 12
#define TOPK 32
#define D 32
#define STOT (T + NF)          // 8200
#define R (H * T)              // 96 score rows per batch
#define KSEL 48                // selection margin (bf16 keys -> exact fp32 rescore)
#define SCALE 0.17677669529663687f

typedef unsigned int uint;
typedef unsigned short ushort;
typedef short bf16x8 __attribute__((ext_vector_type(8)));
typedef float f32x4 __attribute__((ext_vector_type(4)));
typedef float f32x2 __attribute__((ext_vector_type(2)));

__device__ __forceinline__ ushort bf16u(float a) {
  return __builtin_bit_cast(ushort, __float2bfloat16(a));
}

// order-preserving u16 key from f32 (bf16 RNE, sign-flip encode)
__device__ __forceinline__ ushort f32_key(float s) {
  uint kb = bf16u(s);
  kb ^= (kb & 0x8000u) ? 0xFFFFu : 0x8000u;
  return (ushort)kb;
}

// ---------------------------------------------------------------------------
// Kernel 1a: q-projection. grid (T, 6 o-tiles, 2 k-halves), 256 thr.
// ---------------------------------------------------------------------------
__global__ __launch_bounds__(256) void ta_qproj_kernel(
    const float* __restrict__ x, const float* __restrict__ qs_w,
    float* __restrict__ q_part) {
  int t = blockIdx.x;
  int o0 = blockIdx.y * 64;
  int z = blockIdx.z;
  int tid = threadIdx.x;
  int o = tid & 63, ks = tid >> 6;
  __shared__ float xs[B][192];
  __shared__ float part[4][B][64];
  if (tid < 192) {
    int b = tid / 48, j4 = (tid % 48) * 4;
    *reinterpret_cast<float4*>(&xs[b][j4]) =
        *reinterpret_cast<const float4*>(x + ((size_t)b * STOT + t) * C + z * 192 + j4);
  }
  __syncthreads();
  float a0 = 0.f, a1 = 0.f, a2 = 0.f, a3 = 0.f;
  const float* w = qs_w + (size_t)t * C * C + (size_t)(z * 192 + ks * 48) * C + o0 + o;
#pragma unroll 8
  for (int c = 0; c < 48; ++c) {
    float wv = w[(size_t)c * C];
    int cj = ks * 48 + c;
    a0 += xs[0][cj] * wv;
    a1 += xs[1][cj] * wv;
    a2 += xs[2][cj] * wv;
    a3 += xs[3][cj] * wv;
  }
  part[ks][0][o] = a0; part[ks][1][o] = a1;
  part[ks][2][o] = a2; part[ks][3][o] = a3;
  __syncthreads();
  {
    int b = tid >> 6, oo = tid & 63;
    float s = part[0][b][oo] + part[1][b][oo] + part[2][b][oo] + part[3][b][oo];
    q_part[(((size_t)z * B + b) * T + t) * C + o0 + oo] = s;
  }
}

// ---------------------------------------------------------------------------
// Kernel 1b: fold k-projection. grid B*H, 384 thr (thread = c).
// ---------------------------------------------------------------------------
__global__ __launch_bounds__(384) void ta_fold_kernel(
    const float* __restrict__ q_part, const float* __restrict__ kv_w,
    float* __restrict__ qk_f32, ushort* __restrict__ qk_bf) {
  int b = blockIdx.x / H, h = blockIdx.x % H;
  int tid = threadIdx.x;
  __shared__ float kS[C][33];
  __shared__ float qh[T][D];
  if (tid < T * D) {
    int t = tid >> 5, d = tid & 31;
    qh[t][d] = q_part[((size_t)b * T + t) * C + h * D + d] +
               q_part[(((size_t)B + b) * T + t) * C + h * D + d];
  }
  for (int j = tid; j < C * 8; j += 384) {
    int c = j >> 3, d4 = (j & 7) * 4;
    float4 v = *reinterpret_cast<const float4*>(
        kv_w + (size_t)c * (2 * C) + h * D + d4);
    kS[c][d4 + 0] = v.x; kS[c][d4 + 1] = v.y;
    kS[c][d4 + 2] = v.z; kS[c][d4 + 3] = v.w;
  }
  __syncthreads();
  float acc[T] = {0.f, 0.f, 0.f, 0.f, 0.f, 0.f, 0.f, 0.f};
#pragma unroll
  for (int d = 0; d < D; ++d) {
    float kv = kS[tid][d];
#pragma unroll
    for (int t = 0; t < T; ++t) acc[t] += qh[t][d] * kv;
  }
#pragma unroll
  for (int t = 0; t < T; ++t) {
    size_t off = ((size_t)b * R + (size_t)h * T + t) * C + tid;
    float a = acc[t];
    qk_f32[off] = a;
    qk_bf[off] = bf16u(a);
  }
}

// ---------------------------------------------------------------------------
// Kernel 2: bf16 MFMA scores -> u16 sort-keys + overlapped d_out zeroing.
// ---------------------------------------------------------------------------
__global__ __launch_bounds__(256) void ta_scores_kernel(
    const float* __restrict__ x, const ushort* __restrict__ qk_bf,
    ushort* __restrict__ keys, float4* __restrict__ out4) {
  int b = blockIdx.y;
  int n0 = blockIdx.x * 64;
  int tid = threadIdx.x;
  int lane = tid & 63, w = tid >> 6;
  int row16 = lane & 15, kg = lane >> 4;
  __shared__ ushort fS[64][72];
  __shared__ ushort qS[96][72];
  f32x4 acc[6];
#pragma unroll
  for (int i = 0; i < 6; ++i) acc[i] = (f32x4){0.f, 0.f, 0.f, 0.f};

  // zero my slice of d_out; stores drain under the MFMA loop below.
  {
    const int SL = (B * STOT * C / 4) / 512;  // 6150
    int zbid = blockIdx.y * gridDim.x + blockIdx.x;
    float4 z = {0.f, 0.f, 0.f, 0.f};
    float4* dst = out4 + (size_t)zbid * SL;
    for (int j = tid; j < SL; j += 256) dst[j] = z;
  }

  const float* xb = x + ((size_t)b * STOT + T + n0) * C;
  const ushort* qb = qk_bf + (size_t)b * R * C;

  int frow = tid >> 2, fcg = (tid & 3) * 8;

#pragma unroll 1
  for (int c0 = 0; c0 < C; c0 += 32) {
    {
      const float* src = xb + (size_t)frow * C + c0 + fcg;
      float4 v0 = *reinterpret_cast<const float4*>(src);
      float4 v1 = *reinterpret_cast<const float4*>(src + 4);
      uint4 p;
      p.x = (uint)bf16u(v0.x) | ((uint)bf16u(v0.y) << 16);
      p.y = (uint)bf16u(v0.z) | ((uint)bf16u(v0.w) << 16);
      p.z = (uint)bf16u(v1.x) | ((uint)bf16u(v1.y) << 16);
      p.w = (uint)bf16u(v1.z) | ((uint)bf16u(v1.w) << 16);
      *reinterpret_cast<uint4*>(&fS[frow][fcg]) = p;
    }
#pragma unroll
    for (int s = 0; s < 2; ++s) {
      int u = tid + 256 * s;
      if (u < 384) {
        int row = u >> 2, cg = (u & 3) * 8;
        uint4 v = *reinterpret_cast<const uint4*>(qb + (size_t)row * C + c0 + cg);
        *reinterpret_cast<uint4*>(&qS[row][cg]) = v;
      }
    }
    __syncthreads();
    bf16x8 bfr = *reinterpret_cast<const bf16x8*>(&fS[w * 16 + row16][kg * 8]);
#pragma unroll
    for (int i = 0; i < 6; ++i) {
      bf16x8 afr = *reinterpret_cast<const bf16x8*>(&qS[i * 16 + row16][kg * 8]);
      acc[i] = __builtin_amdgcn_mfma_f32_16x16x32_bf16(afr, bfr, acc[i], 0, 0, 0);
    }
    __syncthreads();
  }
  int n = n0 + w * 16 + row16;
#pragma unroll
  for (int i = 0; i < 6; ++i) {
    int rbase = i * 16 + kg * 4;
#pragma unroll
    for (int reg = 0; reg < 4; ++reg) {
      keys[((size_t)b * R + rbase + reg) * NF + n] = f32_key(acc[i][reg] * SCALE);
    }
  }
}

// ---------------------------------------------------------------------------
// Kernel 3: select via ONE 4096-bin histogram pass + packed-rank, then exact
// fp32 rescore + softmax. One block per score row, 384 threads.
// ---------------------------------------------------------------------------
__global__ __launch_bounds__(384) void ta_selres_kernel(
    const ushort* __restrict__ keys, const float* __restrict__ x,
    const float* __restrict__ qk_f32, float* __restrict__ w_buf,
    int* __restrict__ idx_buf) {
  int rr = blockIdx.x;
  int b = rr / R;
  int tid = threadIdx.x;
  int lane = tid & 63, wvi = tid >> 6;   // 6 waves (scan uses waves 0..3)
  __shared__ __align__(16) ushort su[NF];   // 16 KB
  __shared__ uint hist[4096];               // 16 KB (12-bit bins)
  __shared__ uint cand[1024];               // packed (key<<13)|(8191-idx)
  __shared__ uint wtot[4];
  __shared__ uint sh_piv, sh_above, cnt;
  __shared__ int il[KSEL];
  __shared__ float sv[KSEL];
  __shared__ int rkS[KSEL];
  __shared__ float qS[C];
  __shared__ float smax, esum;

  {
    const uint4* src = reinterpret_cast<const uint4*>(keys + (size_t)rr * NF);
    uint4* dst = reinterpret_cast<uint4*>(su);
    for (int j = tid; j < NF / 8; j += 384) dst[j] = src[j];
  }
  qS[tid] = qk_f32[(size_t)rr * C + tid];
  for (int i = tid; i < 4096; i += 384) hist[i] = 0;
  if (tid == 0) cnt = 0;
  __syncthreads();

  // single histogram pass on 12-bit prefix
  for (int i = tid; i < NF; i += 384) atomicAdd(&hist[su[i] >> 4], 1u);
  __syncthreads();

  // suffix-scan over 4096 bins: thread t (t<256) owns bins [16t, 16t+16)
  uint pp = 0, suf = 0;
  if (tid < 256) {
#pragma unroll
    for (int j = 0; j < 16; ++j) pp += hist[tid * 16 + j];
    suf = pp;
#pragma unroll
    for (int off = 1; off < 64; off <<= 1) {
      uint o = __shfl_down(suf, off);
      if (lane + off < 64) suf += o;
    }
    if (lane == 0) wtot[wvi] = suf;
  }
  __syncthreads();
  if (tid < 256) {
    uint later = 0;
    for (int wq = wvi + 1; wq < 4; ++wq) later += wtot[wq];
    uint geg = later + suf;        // sum of bins >= 16*tid
    uint gng = geg - pp;           // sum of bins >= 16*(tid+1)
    if (geg >= (uint)KSEL && gng < (uint)KSEL) {
      uint run = gng;
      int pv = 0; uint ab = 0;
      for (int j = 15; j >= 0; --j) {
        uint c = hist[tid * 16 + j];
        uint nrun = run + c;
        if (nrun >= (uint)KSEL && run < (uint)KSEL) { pv = tid * 16 + j; ab = run; }
        run = nrun;
      }
      sh_piv = (uint)pv; sh_above = ab;
    }
  }
  __syncthreads();
  uint piv = sh_piv;
  // collect all candidates with 12-bit prefix >= piv (m = above + eq-bin count)
  for (int i = tid; i < NF; i += 384) {
    uint u = su[i];
    if ((u >> 4) >= piv) {
      uint s = atomicAdd(&cnt, 1u);
      if (s < 1024) cand[s] = (u << 13) | (8191u - (uint)i);
    }
  }
  __syncthreads();
  {
    uint m = cnt < 1024u ? cnt : 1024u;
    if (tid < (int)m) {
      uint me = cand[tid];
      int r = 0;
      for (uint e = 0; e < m; ++e) r += (cand[e] > me);
      if (r < KSEL) il[r] = 8191 - (int)(me & 8191u);
    }
  }
  __syncthreads();

  // exact fp32 rescore of the 48 candidates (8 threads per candidate)
  int k = tid >> 3, j = tid & 7;
  const float* fp = x + ((size_t)b * STOT + T + il[k]) * C + j;
  float s = 0.f;
#pragma unroll 8
  for (int m2 = 0; m2 < 48; ++m2) s += fp[m2 * 8] * qS[j + m2 * 8];
  s += __shfl_down(s, 4);
  s += __shfl_down(s, 2);
  s += __shfl_down(s, 1);
  if (j == 0) sv[k] = s * SCALE;
  __syncthreads();
  if (tid < KSEL) {
    float mys = sv[tid];
    int myn = il[tid];
    int r = 0;
#pragma unroll
    for (int e = 0; e < KSEL; ++e) {
      float se = sv[e];
      r += (se > mys) || (se == mys && il[e] < myn);
    }
    rkS[tid] = r;
    if (r == 0) smax = mys;
  }
  __syncthreads();
  float e = 0.f;
  if (tid < KSEL && rkS[tid] < TOPK) e = expf(sv[tid] - smax);
  if (tid < 64) {
    float t2 = e;
#pragma unroll
    for (int off = 32; off; off >>= 1) t2 += __shfl_down(t2, off);
    if (tid == 0) esum = t2;
  }
  __syncthreads();
  if (tid < KSEL && rkS[tid] < TOPK) {
    w_buf[(size_t)rr * TOPK + rkS[tid]] = e / esum;
    idx_buf[(size_t)rr * TOPK + rkS[tid]] = il[tid];
  }
}

// ---------------------------------------------------------------------------
// Kernel 4: gv + scatter, split by k-half (grid = 768). 256 thr = 16 k x
// 16 lanes (2 d each). att contribution is linear in k -> each half
// atomically adds its own share.
// ---------------------------------------------------------------------------
__global__ __launch_bounds__(256) void ta_gvscatter_kernel(
    const float* __restrict__ x, const float* __restrict__ kv_w,
    const float* __restrict__ ew, const float* __restrict__ w_buf,
    const int* __restrict__ idx_buf, float* __restrict__ out) {
  constexpr int KH = TOPK / 2;  // 16
  int br = blockIdx.x >> 1, half = blockIdx.x & 1;
  int t = br % T, h = (br / T) % H, b = br / R;
  int tid = threadIdx.x;
  int k16 = tid >> 4, lane16 = tid & 15, d0 = 2 * lane16;
  __shared__ float Fc[KH][100];     // 6.4 KB
  __shared__ float Vc[96][36];      // 13.8 KB
  __shared__ float vS[KH][36];      // 2.3 KB
  __shared__ float gS[KH][36];      // 2.3 KB
  __shared__ __align__(16) float attS[D];
  __shared__ float wl[KH];
  __shared__ int il[KH];

  if (tid < KH) {
    wl[tid] = w_buf[(size_t)br * TOPK + half * KH + tid];
    il[tid] = idx_buf[(size_t)br * TOPK + half * KH + tid];
  }
  __syncthreads();
  f32x2 acc = {0.f, 0.f};
  int hc = (h * D) / 96;   // chunk containing [hD, hD+32)
#pragma unroll 1
  for (int ch = 0; ch < 4; ++ch) {
    int c0 = ch * 96;
    if (ch) __syncthreads();
    // stage Fc: 16 rows x 24 float4 = 384 jobs
#pragma unroll
    for (int s = 0; s < 2; ++s) {
      int u = tid + 256 * s;
      if (u < 384) {
        int kr = u / 24, c4 = (u % 24) * 4;
        *reinterpret_cast<float4*>(&Fc[kr][c4]) =
            *reinterpret_cast<const float4*>(
                x + ((size_t)b * STOT + T + il[kr]) * C + c0 + c4);
      }
    }
    // stage Vc: 96 rows x 8 float4 = 768 jobs
#pragma unroll
    for (int s = 0; s < 3; ++s) {
      int u = tid + 256 * s;
      int cr = u >> 3, d4 = (u & 7) * 4;
      *reinterpret_cast<float4*>(&Vc[cr][d4]) =
          *reinterpret_cast<const float4*>(
              kv_w + (size_t)(c0 + cr) * (2 * C) + C + h * D + d4);
    }
    __syncthreads();
    if (ch == hc) {  // g[k][d] = wl[k] * F[k][hD+d]
      int off = h * D - c0;
      f32x2 f = *reinterpret_cast<const f32x2*>(&Fc[k16][off + d0]);
      float wk = wl[k16];
      gS[k16][d0] = wk * f.x;
      gS[k16][d0 + 1] = wk * f.y;
    }
#pragma unroll 4
    for (int c = 0; c < 96; c += 4) {
      float4 f4 = *reinterpret_cast<const float4*>(&Fc[k16][c]);
      f32x2 v0 = *reinterpret_cast<const f32x2*>(&Vc[c + 0][d0]);
      f32x2 v1 = *reinterpret_cast<const f32x2*>(&Vc[c + 1][d0]);
      f32x2 v2 = *reinterpret_cast<const f32x2*>(&Vc[c + 2][d0]);
      f32x2 v3 = *reinterpret_cast<const f32x2*>(&Vc[c + 3][d0]);
      acc.x += f4.x * v0.x + f4.y * v1.x + f4.z * v2.x + f4.w * v3.x;
      acc.y += f4.x * v0.y + f4.y * v1.y + f4.z * v2.y + f4.w * v3.y;
    }
  }
  vS[k16][d0] = acc.x;
  vS[k16][d0 + 1] = acc.y;
  __syncthreads();
  if (tid < D) {
    float a = 0.f;
#pragma unroll
    for (int kk = 0; kk < KH; ++kk) a += wl[kk] * vS[kk][tid];
    attS[tid] = a;   // this half's share of att
  }
  __syncthreads();

  // ---- scatter: columns o0 = tid, o1 = tid + 256 (tid < 128) ----
  float ewc0[D], ewc1[D];
  const float* ewt = ew + (size_t)t * C * C + (size_t)h * D * C;
#pragma unroll
  for (int dd = 0; dd < D; ++dd) {
    ewc0[dd] = ewt[(size_t)dd * C + tid];
    ewc1[dd] = (tid < 128) ? ewt[(size_t)dd * C + tid + 256] : 0.f;
  }
  size_t obase = (size_t)b * STOT * C;
#pragma unroll 1
  for (int kk = 0; kk < KH; ++kk) {
    float y0 = 0.f, y1 = 0.f;
#pragma unroll
    for (int d4 = 0; d4 < D; d4 += 4) {
      float4 g4 = *reinterpret_cast<const float4*>(&gS[kk][d4]);
      y0 += g4.x * ewc0[d4] + g4.y * ewc0[d4 + 1] +
            g4.z * ewc0[d4 + 2] + g4.w * ewc0[d4 + 3];
      y1 += g4.x * ewc1[d4] + g4.y * ewc1[d4 + 1] +
            g4.z * ewc1[d4 + 2] + g4.w * ewc1[d4 + 3];
    }
    size_t row = obase + (size_t)(T + il[kk]) * C;
    atomicAdd(&out[row + tid], y0);
    if (tid < 128) atomicAdd(&out[row + tid + 256], y1);
  }
  {
    float y0 = 0.f, y1 = 0.f;
#pragma unroll
    for (int d4 = 0; d4 < D; d4 += 4) {
      float4 a4 = *reinterpret_cast<const float4*>(attS + d4);
      y0 += a4.x * ewc0[d4] + a4.y * ewc0[d4 + 1] +
            a4.z * ewc0[d4 + 2] + a4.w * ewc0[d4 + 3];
      y1 += a4.x * ewc1[d4] + a4.y * ewc1[d4 + 1] +
            a4.z * ewc1[d4 + 2] + a4.w * ewc1[d4 + 3];
    }
    size_t row = obase + (size_t)t * C;
    atomicAdd(&out[row + tid], y0);
    if (tid < 128) atomicAdd(&out[row + tid + 256], y1);
  }
}

// ---------------------------------------------------------------------------
extern "C" void kernel_launch(void* const* d_in, const int* in_sizes, int n_in,
                              void* d_out, int out_size, void* d_ws, size_t ws_size,
                              hipStream_t stream) {
  const float* x = (const float*)d_in[0];
  const float* qs_w = (const float*)d_in[1];
  const float* kv_w = (const float*)d_in[2];
  const float* ew = (const float*)d_in[3];
  float* out = (float*)d_out;

  char* p = (char*)d_ws;
  float* qk_f32 = (float*)p;  p += (size_t)B * R * C * 4;        // 589824
  ushort* qk_bf = (ushort*)p; p += (size_t)B * R * C * 2;        // 294912
  ushort* keys = (ushort*)p;  p += (size_t)B * R * NF * 2;       // 6291456
  float* w_buf = (float*)p;   p += (size_t)B * R * TOPK * 4;     // 49152
  int* idx_buf = (int*)p;     p += (size_t)B * R * TOPK * 4;     // 49152
  float* q_part = (float*)p;  // 2*B*T*C floats

  dim3 gq(T, C / 64, 2);
  ta_qproj_kernel<<<gq, 256, 0, stream>>>(x, qs_w, q_part);
  ta_fold_kernel<<<B * H, 384, 0, stream>>>(q_part, kv_w, qk_f32, qk_bf);
  dim3 g2(NF / 64, B);
  ta_scores_kernel<<<g2, 256, 0, stream>>>(x, qk_bf, keys, (float4*)out);
  ta_selres_kernel<<<B * R, 384, 0, stream>>>(keys, x, qk_f32, w_buf, idx_buf);
  ta_gvscatter_kernel<<<B * R * 2, 256, 0, stream>>>(x, kv_w, ew, w_buf, idx_buf, out);
}

// Round 11
// 80.478 us; speedup vs baseline: 1.1582x; 1.0890x over previous
//
#include <hip/hip_runtime.h>
#include <hip/hip_bf16.h>
#include <math.h>

#define B 4
#define T 8
#define NF 8192
#define C 384
#define H 12
#define TOPK 32
#define D 32
#define STOT (T + NF)          // 8200
#define R (H * T)              // 96 score rows per batch
#define KSEL 48                // selection margin (bf16 keys -> exact fp32 rescore)
#define SCALE 0.17677669529663687f

typedef unsigned int uint;
typedef unsigned short ushort;
typedef short bf16x8 __attribute__((ext_vector_type(8)));
typedef float f32x4 __attribute__((ext_vector_type(4)));

__device__ __forceinline__ ushort bf16u(float a) {
  return __builtin_bit_cast(ushort, __float2bfloat16(a));
}

// order-preserving u16 key from f32 (bf16 RNE, sign-flip encode)
__device__ __forceinline__ ushort f32_key(float s) {
  uint kb = bf16u(s);
  kb ^= (kb & 0x8000u) ? 0xFFFFu : 0x8000u;
  return (ushort)kb;
}

// ---------------------------------------------------------------------------
// Kernel 1a: q-projection. grid (T, 6 o-tiles, 2 k-halves), 256 thr.
// ---------------------------------------------------------------------------
__global__ __launch_bounds__(256) void ta_qproj_kernel(
    const float* __restrict__ x, const float* __restrict__ qs_w,
    float* __restrict__ q_part) {
  int t = blockIdx.x;
  int o0 = blockIdx.y * 64;
  int z = blockIdx.z;
  int tid = threadIdx.x;
  int o = tid & 63, ks = tid >> 6;
  __shared__ float xs[B][192];
  __shared__ float part[4][B][64];
  if (tid < 192) {
    int b = tid / 48, j4 = (tid % 48) * 4;
    *reinterpret_cast<float4*>(&xs[b][j4]) =
        *reinterpret_cast<const float4*>(x + ((size_t)b * STOT + t) * C + z * 192 + j4);
  }
  __syncthreads();
  float a0 = 0.f, a1 = 0.f, a2 = 0.f, a3 = 0.f;
  const float* w = qs_w + (size_t)t * C * C + (size_t)(z * 192 + ks * 48) * C + o0 + o;
#pragma unroll 8
  for (int c = 0; c < 48; ++c) {
    float wv = w[(size_t)c * C];
    int cj = ks * 48 + c;
    a0 += xs[0][cj] * wv;
    a1 += xs[1][cj] * wv;
    a2 += xs[2][cj] * wv;
    a3 += xs[3][cj] * wv;
  }
  part[ks][0][o] = a0; part[ks][1][o] = a1;
  part[ks][2][o] = a2; part[ks][3][o] = a3;
  __syncthreads();
  {
    int b = tid >> 6, oo = tid & 63;
    float s = part[0][b][oo] + part[1][b][oo] + part[2][b][oo] + part[3][b][oo];
    q_part[(((size_t)z * B + b) * T + t) * C + o0 + oo] = s;
  }
}

// ---------------------------------------------------------------------------
// Kernel 1b: fold k-projection. grid B*H, 384 thr (thread = c).
// ---------------------------------------------------------------------------
__global__ __launch_bounds__(384) void ta_fold_kernel(
    const float* __restrict__ q_part, const float* __restrict__ kv_w,
    float* __restrict__ qk_f32, ushort* __restrict__ qk_bf) {
  int b = blockIdx.x / H, h = blockIdx.x % H;
  int tid = threadIdx.x;
  __shared__ float kS[C][33];
  __shared__ float qh[T][D];
  if (tid < T * D) {
    int t = tid >> 5, d = tid & 31;
    qh[t][d] = q_part[((size_t)b * T + t) * C + h * D + d] +
               q_part[(((size_t)B + b) * T + t) * C + h * D + d];
  }
  for (int j = tid; j < C * 8; j += 384) {
    int c = j >> 3, d4 = (j & 7) * 4;
    float4 v = *reinterpret_cast<const float4*>(
        kv_w + (size_t)c * (2 * C) + h * D + d4);
    kS[c][d4 + 0] = v.x; kS[c][d4 + 1] = v.y;
    kS[c][d4 + 2] = v.z; kS[c][d4 + 3] = v.w;
  }
  __syncthreads();
  float acc[T] = {0.f, 0.f, 0.f, 0.f, 0.f, 0.f, 0.f, 0.f};
#pragma unroll
  for (int d = 0; d < D; ++d) {
    float kv = kS[tid][d];
#pragma unroll
    for (int t = 0; t < T; ++t) acc[t] += qh[t][d] * kv;
  }
#pragma unroll
  for (int t = 0; t < T; ++t) {
    size_t off = ((size_t)b * R + (size_t)h * T + t) * C + tid;
    float a = acc[t];
    qk_f32[off] = a;
    qk_bf[off] = bf16u(a);
  }
}

// ---------------------------------------------------------------------------
// Kernel 2: bf16 MFMA scores -> u16 sort-keys + overlapped d_out zeroing.
// ---------------------------------------------------------------------------
__global__ __launch_bounds__(256) void ta_scores_kernel(
    const float* __restrict__ x, const ushort* __restrict__ qk_bf,
    ushort* __restrict__ keys, float4* __restrict__ out4) {
  int b = blockIdx.y;
  int n0 = blockIdx.x * 64;
  int tid = threadIdx.x;
  int lane = tid & 63, w = tid >> 6;
  int row16 = lane & 15, kg = lane >> 4;
  __shared__ ushort fS[64][72];
  __shared__ ushort qS[96][72];
  f32x4 acc[6];
#pragma unroll
  for (int i = 0; i < 6; ++i) acc[i] = (f32x4){0.f, 0.f, 0.f, 0.f};

  // zero my slice of d_out; stores drain under the MFMA loop below.
  {
    const int SL = (B * STOT * C / 4) / 512;  // 6150
    int zbid = blockIdx.y * gridDim.x + blockIdx.x;
    float4 z = {0.f, 0.f, 0.f, 0.f};
    float4* dst = out4 + (size_t)zbid * SL;
    for (int j = tid; j < SL; j += 256) dst[j] = z;
  }

  const float* xb = x + ((size_t)b * STOT + T + n0) * C;
  const ushort* qb = qk_bf + (size_t)b * R * C;

  int frow = tid >> 2, fcg = (tid & 3) * 8;

#pragma unroll 1
  for (int c0 = 0; c0 < C; c0 += 32) {
    {
      const float* src = xb + (size_t)frow * C + c0 + fcg;
      float4 v0 = *reinterpret_cast<const float4*>(src);
      float4 v1 = *reinterpret_cast<const float4*>(src + 4);
      uint4 p;
      p.x = (uint)bf16u(v0.x) | ((uint)bf16u(v0.y) << 16);
      p.y = (uint)bf16u(v0.z) | ((uint)bf16u(v0.w) << 16);
      p.z = (uint)bf16u(v1.x) | ((uint)bf16u(v1.y) << 16);
      p.w = (uint)bf16u(v1.z) | ((uint)bf16u(v1.w) << 16);
      *reinterpret_cast<uint4*>(&fS[frow][fcg]) = p;
    }
#pragma unroll
    for (int s = 0; s < 2; ++s) {
      int u = tid + 256 * s;
      if (u < 384) {
        int row = u >> 2, cg = (u & 3) * 8;
        uint4 v = *reinterpret_cast<const uint4*>(qb + (size_t)row * C + c0 + cg);
        *reinterpret_cast<uint4*>(&qS[row][cg]) = v;
      }
    }
    __syncthreads();
    bf16x8 bfr = *reinterpret_cast<const bf16x8*>(&fS[w * 16 + row16][kg * 8]);
#pragma unroll
    for (int i = 0; i < 6; ++i) {
      bf16x8 afr = *reinterpret_cast<const bf16x8*>(&qS[i * 16 + row16][kg * 8]);
      acc[i] = __builtin_amdgcn_mfma_f32_16x16x32_bf16(afr, bfr, acc[i], 0, 0, 0);
    }
    __syncthreads();
  }
  int n = n0 + w * 16 + row16;
#pragma unroll
  for (int i = 0; i < 6; ++i) {
    int rbase = i * 16 + kg * 4;
#pragma unroll
    for (int reg = 0; reg < 4; ++reg) {
      keys[((size_t)b * R + rbase + reg) * NF + n] = f32_key(acc[i][reg] * SCALE);
    }
  }
}

// ---------------------------------------------------------------------------
// Kernel 3: select via ONE 4096-bin histogram pass + packed-rank, then exact
// fp32 rescore + softmax. One block per score row, 384 threads.
// ---------------------------------------------------------------------------
__global__ __launch_bounds__(384) void ta_selres_kernel(
    const ushort* __restrict__ keys, const float* __restrict__ x,
    const float* __restrict__ qk_f32, float* __restrict__ w_buf,
    int* __restrict__ idx_buf) {
  int rr = blockIdx.x;
  int b = rr / R;
  int tid = threadIdx.x;
  int lane = tid & 63, wvi = tid >> 6;   // 6 waves (scan uses waves 0..3)
  __shared__ __align__(16) ushort su[NF];   // 16 KB
  __shared__ uint hist[4096];               // 16 KB (12-bit bins)
  __shared__ uint cand[1024];               // packed (key<<13)|(8191-idx)
  __shared__ uint wtot[4];
  __shared__ uint sh_piv, sh_above, cnt;
  __shared__ int il[KSEL];
  __shared__ float sv[KSEL];
  __shared__ int rkS[KSEL];
  __shared__ float qS[C];
  __shared__ float smax, esum;

  {
    const uint4* src = reinterpret_cast<const uint4*>(keys + (size_t)rr * NF);
    uint4* dst = reinterpret_cast<uint4*>(su);
    for (int j = tid; j < NF / 8; j += 384) dst[j] = src[j];
  }
  qS[tid] = qk_f32[(size_t)rr * C + tid];
  for (int i = tid; i < 4096; i += 384) hist[i] = 0;
  if (tid == 0) cnt = 0;
  __syncthreads();

  // single histogram pass on 12-bit prefix
  for (int i = tid; i < NF; i += 384) atomicAdd(&hist[su[i] >> 4], 1u);
  __syncthreads();

  // suffix-scan over 4096 bins: thread t (t<256) owns bins [16t, 16t+16)
  uint pp = 0, suf = 0;
  if (tid < 256) {
#pragma unroll
    for (int j = 0; j < 16; ++j) pp += hist[tid * 16 + j];
    suf = pp;
#pragma unroll
    for (int off = 1; off < 64; off <<= 1) {
      uint o = __shfl_down(suf, off);
      if (lane + off < 64) suf += o;
    }
    if (lane == 0) wtot[wvi] = suf;
  }
  __syncthreads();
  if (tid < 256) {
    uint later = 0;
    for (int wq = wvi + 1; wq < 4; ++wq) later += wtot[wq];
    uint geg = later + suf;        // sum of bins >= 16*tid
    uint gng = geg - pp;           // sum of bins >= 16*(tid+1)
    if (geg >= (uint)KSEL && gng < (uint)KSEL) {
      uint run = gng;
      int pv = 0; uint ab = 0;
      for (int j = 15; j >= 0; --j) {
        uint c = hist[tid * 16 + j];
        uint nrun = run + c;
        if (nrun >= (uint)KSEL && run < (uint)KSEL) { pv = tid * 16 + j; ab = run; }
        run = nrun;
      }
      sh_piv = (uint)pv; sh_above = ab;
    }
  }
  __syncthreads();
  uint piv = sh_piv;
  // collect all candidates with 12-bit prefix >= piv
  for (int i = tid; i < NF; i += 384) {
    uint u = su[i];
    if ((u >> 4) >= piv) {
      uint s = atomicAdd(&cnt, 1u);
      if (s < 1024) cand[s] = (u << 13) | (8191u - (uint)i);
    }
  }
  __syncthreads();
  {
    uint m = cnt < 1024u ? cnt : 1024u;
    if (tid < (int)m) {
      uint me = cand[tid];
      int r = 0;
      for (uint e = 0; e < m; ++e) r += (cand[e] > me);
      if (r < KSEL) il[r] = 8191 - (int)(me & 8191u);
    }
  }
  __syncthreads();

  // exact fp32 rescore of the 48 candidates (8 threads per candidate)
  int k = tid >> 3, j = tid & 7;
  const float* fp = x + ((size_t)b * STOT + T + il[k]) * C + j;
  float s = 0.f;
#pragma unroll 8
  for (int m2 = 0; m2 < 48; ++m2) s += fp[m2 * 8] * qS[j + m2 * 8];
  s += __shfl_down(s, 4);
  s += __shfl_down(s, 2);
  s += __shfl_down(s, 1);
  if (j == 0) sv[k] = s * SCALE;
  __syncthreads();
  if (tid < KSEL) {
    float mys = sv[tid];
    int myn = il[tid];
    int r = 0;
#pragma unroll
    for (int e = 0; e < KSEL; ++e) {
      float se = sv[e];
      r += (se > mys) || (se == mys && il[e] < myn);
    }
    rkS[tid] = r;
    if (r == 0) smax = mys;
  }
  __syncthreads();
  float e = 0.f;
  if (tid < KSEL && rkS[tid] < TOPK) e = expf(sv[tid] - smax);
  if (tid < 64) {
    float t2 = e;
#pragma unroll
    for (int off = 32; off; off >>= 1) t2 += __shfl_down(t2, off);
    if (tid == 0) esum = t2;
  }
  __syncthreads();
  if (tid < KSEL && rkS[tid] < TOPK) {
    w_buf[(size_t)rr * TOPK + rkS[tid]] = e / esum;
    idx_buf[(size_t)rr * TOPK + rkS[tid]] = il[tid];
  }
}

// ---------------------------------------------------------------------------
// Kernel 4: linearity-collapsed tail. Grid = 768 (br x k-half), 384 thr
// (thread = column c / output col o). Per block:
//   fbar[c] = sum_{k in half} w_k * feat[idx_k][c]   (16 coalesced row loads)
//   att_share[d] = sum_c fbar[c] * Vw[c][hD+d]       (8-seg LDS reduce)
//   g[k][d] = w_k * feat[idx_k][hD+d]                (extracted during loop)
//   scatter: 16 g-rows + att_share row via register-ewc, atomicAdd.
// ---------------------------------------------------------------------------
__global__ __launch_bounds__(384) void ta_gvscatter_kernel(
    const float* __restrict__ x, const float* __restrict__ kv_w,
    const float* __restrict__ ew, const float* __restrict__ w_buf,
    const int* __restrict__ idx_buf, float* __restrict__ out) {
  constexpr int KH = TOPK / 2;  // 16
  int br = blockIdx.x >> 1, half = blockIdx.x & 1;
  int t = br % T, h = (br / T) % H, b = br / R;
  int tid = threadIdx.x;  // = c column (and output col o)
  int hD = h * D;
  __shared__ float wl[KH];
  __shared__ int il[KH];
  __shared__ float fbarS[C];
  __shared__ float gS[KH][D];       // 2 KB (row stride 128 B, float4-aligned)
  __shared__ float part[8][D];
  __shared__ __align__(16) float attS[D];

  if (tid < KH) {
    wl[tid] = w_buf[(size_t)br * TOPK + half * KH + tid];
    il[tid] = idx_buf[(size_t)br * TOPK + half * KH + tid];
  }
  __syncthreads();

  // fbar accumulation + g extraction (threads hD..hD+31 own the g columns)
  {
    float fbar = 0.f;
    bool ing = (tid >= hD) && (tid < hD + D);
#pragma unroll 4
    for (int k = 0; k < KH; ++k) {
      float v = x[((size_t)b * STOT + T + il[k]) * C + tid];
      float wv = wl[k] * v;
      fbar += wv;
      if (ing) gS[k][tid - hD] = wv;
    }
    fbarS[tid] = fbar;
  }
  __syncthreads();

  // att share: 256 threads = 32 d x 8 segs of 48 c; Vw reads 128B-coalesced
  if (tid < 256) {
    int d = tid & 31, seg = tid >> 5;
    const float* vw = kv_w + C + hD + d;   // kv_w[c][C+hD+d], row stride 2C
    float a0 = 0.f, a1 = 0.f;
    int cb = seg * 48;
#pragma unroll 8
    for (int c = 0; c < 48; c += 2) {
      a0 += fbarS[cb + c] * vw[(size_t)(cb + c) * (2 * C)];
      a1 += fbarS[cb + c + 1] * vw[(size_t)(cb + c + 1) * (2 * C)];
    }
    part[seg][d] = a0 + a1;
  }
  __syncthreads();
  if (tid < D) {
    float a = 0.f;
#pragma unroll
    for (int s = 0; s < 8; ++s) a += part[s][tid];
    attS[tid] = a;   // this half's share of att
  }
  __syncthreads();

  // scatter: thread = output column o = tid
  float ewc[D];
  const float* ewt = ew + (size_t)t * C * C + (size_t)hD * C + tid;
#pragma unroll
  for (int dd = 0; dd < D; ++dd) ewc[dd] = ewt[(size_t)dd * C];
  size_t obase = (size_t)b * STOT * C + tid;
#pragma unroll 1
  for (int kk = 0; kk < KH; ++kk) {
    float y = 0.f;
#pragma unroll
    for (int d4 = 0; d4 < D; d4 += 4) {
      float4 g4 = *reinterpret_cast<const float4*>(&gS[kk][d4]);
      y += g4.x * ewc[d4] + g4.y * ewc[d4 + 1] +
           g4.z * ewc[d4 + 2] + g4.w * ewc[d4 + 3];
    }
    atomicAdd(&out[obase + (size_t)(T + il[kk]) * C], y);
  }
  {
    float y = 0.f;
#pragma unroll
    for (int d4 = 0; d4 < D; d4 += 4) {
      float4 a4 = *reinterpret_cast<const float4*>(attS + d4);
      y += a4.x * ewc[d4] + a4.y * ewc[d4 + 1] +
           a4.z * ewc[d4 + 2] + a4.w * ewc[d4 + 3];
    }
    atomicAdd(&out[obase + (size_t)t * C], y);
  }
}

// ---------------------------------------------------------------------------
extern "C" void kernel_launch(void* const* d_in, const int* in_sizes, int n_in,
                              void* d_out, int out_size, void* d_ws, size_t ws_size,
                              hipStream_t stream) {
  const float* x = (const float*)d_in[0];
  const float* qs_w = (const float*)d_in[1];
  const float* kv_w = (const float*)d_in[2];
  const float* ew = (const float*)d_in[3];
  float* out = (float*)d_out;

  char* p = (char*)d_ws;
  float* qk_f32 = (float*)p;  p += (size_t)B * R * C * 4;        // 589824
  ushort* qk_bf = (ushort*)p; p += (size_t)B * R * C * 2;        // 294912
  ushort* keys = (ushort*)p;  p += (size_t)B * R * NF * 2;       // 6291456
  float* w_buf = (float*)p;   p += (size_t)B * R * TOPK * 4;     // 49152
  int* idx_buf = (int*)p;     p += (size_t)B * R * TOPK * 4;     // 49152
  float* q_part = (float*)p;  // 2*B*T*C floats

  dim3 gq(T, C / 64, 2);
  ta_qproj_kernel<<<gq, 256, 0, stream>>>(x, qs_w, q_part);
  ta_fold_kernel<<<B * H, 384, 0, stream>>>(q_part, kv_w, qk_f32, qk_bf);
  dim3 g2(NF / 64, B);
  ta_scores_kernel<<<g2, 256, 0, stream>>>(x, qk_bf, keys, (float4*)out);
  ta_selres_kernel<<<B * R, 384, 0, stream>>>(keys, x, qk_f32, w_buf, idx_buf);
  ta_gvscatter_kernel<<<B * R * 2, 384, 0, stream>>>(x, kv_w, ew, w_buf, idx_buf, out);
}

// Round 12
// 79.957 us; speedup vs baseline: 1.1658x; 1.0065x over previous
//
#include <hip/hip_runtime.h>
#include <hip/hip_bf16.h>
#include <math.h>

#define B 4
#define T 8
#define NF 8192
#define C 384
#define H 12
#define TOPK 32
#define D 32
#define STOT (T + NF)          // 8200
#define R (H * T)              // 96 score rows per batch
#define KSEL 48                // selection margin (bf16 keys -> exact fp32 rescore)
#define SCALE 0.17677669529663687f

typedef unsigned int uint;
typedef unsigned short ushort;
typedef short bf16x8 __attribute__((ext_vector_type(8)));
typedef float f32x4 __attribute__((ext_vector_type(4)));

__device__ __forceinline__ ushort bf16u(float a) {
  return __builtin_bit_cast(ushort, __float2bfloat16(a));
}

// order-preserving u16 key from f32 (bf16 RNE, sign-flip encode)
__device__ __forceinline__ ushort f32_key(float s) {
  uint kb = bf16u(s);
  kb ^= (kb & 0x8000u) ? 0xFFFFu : 0x8000u;
  return (ushort)kb;
}

// ---------------------------------------------------------------------------
// Kernel 1a: q-projection. grid (T, 6 o-tiles, 2 k-halves), 256 thr.
// ---------------------------------------------------------------------------
__global__ __launch_bounds__(256) void ta_qproj_kernel(
    const float* __restrict__ x, const float* __restrict__ qs_w,
    float* __restrict__ q_part) {
  int t = blockIdx.x;
  int o0 = blockIdx.y * 64;
  int z = blockIdx.z;
  int tid = threadIdx.x;
  int o = tid & 63, ks = tid >> 6;
  __shared__ float xs[B][192];
  __shared__ float part[4][B][64];
  if (tid < 192) {
    int b = tid / 48, j4 = (tid % 48) * 4;
    *reinterpret_cast<float4*>(&xs[b][j4]) =
        *reinterpret_cast<const float4*>(x + ((size_t)b * STOT + t) * C + z * 192 + j4);
  }
  __syncthreads();
  float a0 = 0.f, a1 = 0.f, a2 = 0.f, a3 = 0.f;
  const float* w = qs_w + (size_t)t * C * C + (size_t)(z * 192 + ks * 48) * C + o0 + o;
#pragma unroll 8
  for (int c = 0; c < 48; ++c) {
    float wv = w[(size_t)c * C];
    int cj = ks * 48 + c;
    a0 += xs[0][cj] * wv;
    a1 += xs[1][cj] * wv;
    a2 += xs[2][cj] * wv;
    a3 += xs[3][cj] * wv;
  }
  part[ks][0][o] = a0; part[ks][1][o] = a1;
  part[ks][2][o] = a2; part[ks][3][o] = a3;
  __syncthreads();
  {
    int b = tid >> 6, oo = tid & 63;
    float s = part[0][b][oo] + part[1][b][oo] + part[2][b][oo] + part[3][b][oo];
    q_part[(((size_t)z * B + b) * T + t) * C + o0 + oo] = s;
  }
}

// ---------------------------------------------------------------------------
// Kernel 1b: fold k-projection. grid B*H, 384 thr (thread = c).
// ---------------------------------------------------------------------------
__global__ __launch_bounds__(384) void ta_fold_kernel(
    const float* __restrict__ q_part, const float* __restrict__ kv_w,
    float* __restrict__ qk_f32, ushort* __restrict__ qk_bf) {
  int b = blockIdx.x / H, h = blockIdx.x % H;
  int tid = threadIdx.x;
  __shared__ float kS[C][33];
  __shared__ float qh[T][D];
  if (tid < T * D) {
    int t = tid >> 5, d = tid & 31;
    qh[t][d] = q_part[((size_t)b * T + t) * C + h * D + d] +
               q_part[(((size_t)B + b) * T + t) * C + h * D + d];
  }
  for (int j = tid; j < C * 8; j += 384) {
    int c = j >> 3, d4 = (j & 7) * 4;
    float4 v = *reinterpret_cast<const float4*>(
        kv_w + (size_t)c * (2 * C) + h * D + d4);
    kS[c][d4 + 0] = v.x; kS[c][d4 + 1] = v.y;
    kS[c][d4 + 2] = v.z; kS[c][d4 + 3] = v.w;
  }
  __syncthreads();
  float acc[T] = {0.f, 0.f, 0.f, 0.f, 0.f, 0.f, 0.f, 0.f};
#pragma unroll
  for (int d = 0; d < D; ++d) {
    float kv = kS[tid][d];
#pragma unroll
    for (int t = 0; t < T; ++t) acc[t] += qh[t][d] * kv;
  }
#pragma unroll
  for (int t = 0; t < T; ++t) {
    size_t off = ((size_t)b * R + (size_t)h * T + t) * C + tid;
    float a = acc[t];
    qk_f32[off] = a;
    qk_bf[off] = bf16u(a);
  }
}

// ---------------------------------------------------------------------------
// Kernel 2: bf16 MFMA scores -> u16 sort-keys + overlapped d_out zeroing.
// ---------------------------------------------------------------------------
__global__ __launch_bounds__(256) void ta_scores_kernel(
    const float* __restrict__ x, const ushort* __restrict__ qk_bf,
    ushort* __restrict__ keys, float4* __restrict__ out4) {
  int b = blockIdx.y;
  int n0 = blockIdx.x * 64;
  int tid = threadIdx.x;
  int lane = tid & 63, w = tid >> 6;
  int row16 = lane & 15, kg = lane >> 4;
  __shared__ ushort fS[64][72];
  __shared__ ushort qS[96][72];
  f32x4 acc[6];
#pragma unroll
  for (int i = 0; i < 6; ++i) acc[i] = (f32x4){0.f, 0.f, 0.f, 0.f};

  // zero my slice of d_out; stores drain under the MFMA loop below.
  {
    const int SL = (B * STOT * C / 4) / 512;  // 6150
    int zbid = blockIdx.y * gridDim.x + blockIdx.x;
    float4 z = {0.f, 0.f, 0.f, 0.f};
    float4* dst = out4 + (size_t)zbid * SL;
    for (int j = tid; j < SL; j += 256) dst[j] = z;
  }

  const float* xb = x + ((size_t)b * STOT + T + n0) * C;
  const ushort* qb = qk_bf + (size_t)b * R * C;

  int frow = tid >> 2, fcg = (tid & 3) * 8;

#pragma unroll 1
  for (int c0 = 0; c0 < C; c0 += 32) {
    {
      const float* src = xb + (size_t)frow * C + c0 + fcg;
      float4 v0 = *reinterpret_cast<const float4*>(src);
      float4 v1 = *reinterpret_cast<const float4*>(src + 4);
      uint4 p;
      p.x = (uint)bf16u(v0.x) | ((uint)bf16u(v0.y) << 16);
      p.y = (uint)bf16u(v0.z) | ((uint)bf16u(v0.w) << 16);
      p.z = (uint)bf16u(v1.x) | ((uint)bf16u(v1.y) << 16);
      p.w = (uint)bf16u(v1.z) | ((uint)bf16u(v1.w) << 16);
      *reinterpret_cast<uint4*>(&fS[frow][fcg]) = p;
    }
#pragma unroll
    for (int s = 0; s < 2; ++s) {
      int u = tid + 256 * s;
      if (u < 384) {
        int row = u >> 2, cg = (u & 3) * 8;
        uint4 v = *reinterpret_cast<const uint4*>(qb + (size_t)row * C + c0 + cg);
        *reinterpret_cast<uint4*>(&qS[row][cg]) = v;
      }
    }
    __syncthreads();
    bf16x8 bfr = *reinterpret_cast<const bf16x8*>(&fS[w * 16 + row16][kg * 8]);
#pragma unroll
    for (int i = 0; i < 6; ++i) {
      bf16x8 afr = *reinterpret_cast<const bf16x8*>(&qS[i * 16 + row16][kg * 8]);
      acc[i] = __builtin_amdgcn_mfma_f32_16x16x32_bf16(afr, bfr, acc[i], 0, 0, 0);
    }
    __syncthreads();
  }
  int n = n0 + w * 16 + row16;
#pragma unroll
  for (int i = 0; i < 6; ++i) {
    int rbase = i * 16 + kg * 4;
#pragma unroll
    for (int reg = 0; reg < 4; ++reg) {
      keys[((size_t)b * R + rbase + reg) * NF + n] = f32_key(acc[i][reg] * SCALE);
    }
  }
}

// ---------------------------------------------------------------------------
// Kernel 3: fused per-row tail: 4096-bin select -> exact fp32 rescore ->
// softmax -> fbar/g -> att -> scatter. One block per (b,h,t) row, 384 thr.
// Selection LDS (hist/cand) overlaid with tail buffers via union.
// ---------------------------------------------------------------------------
__global__ __launch_bounds__(384) void ta_seltail_kernel(
    const ushort* __restrict__ keys, const float* __restrict__ x,
    const float* __restrict__ qk_f32, const float* __restrict__ kv_w,
    const float* __restrict__ ew, float* __restrict__ out) {
  int rr = blockIdx.x;
  int t = rr % T, h = (rr / T) % H, b = rr / R;
  int hD = h * D;
  int tid = threadIdx.x;
  int lane = tid & 63, wvi = tid >> 6;   // 6 waves (scan uses waves 0..3)

  union SM {
    struct {
      uint hist[4096];        // 16 KB
      uint cand[1024];        // 4 KB packed (key<<13)|(8191-idx)
    } s;
    struct {
      float fbarS[C];
      float gS[TOPK][D];      // 4 KB
      float part[8][D];
    } g;
  };
  __shared__ SM sm;
  __shared__ __align__(16) ushort su[NF];   // 16 KB
  __shared__ uint wtot[4];
  __shared__ uint sh_piv, cnt;
  __shared__ int il[KSEL];
  __shared__ float sv[KSEL];
  __shared__ int rkS[KSEL];
  __shared__ float qS[C];
  __shared__ float wl[TOPK];
  __shared__ int top_il[TOPK];
  __shared__ __align__(16) float attS[D];
  __shared__ float smax, esum;

  {
    const uint4* src = reinterpret_cast<const uint4*>(keys + (size_t)rr * NF);
    uint4* dst = reinterpret_cast<uint4*>(su);
    for (int j = tid; j < NF / 8; j += 384) dst[j] = src[j];
  }
  qS[tid] = qk_f32[(size_t)rr * C + tid];
  {
    uint4 z4 = {0u, 0u, 0u, 0u};
    uint4* hz = reinterpret_cast<uint4*>(sm.s.hist);
    for (int i = tid; i < 1024; i += 384) hz[i] = z4;
  }
  if (tid == 0) cnt = 0;
  __syncthreads();

  // single histogram pass on 12-bit prefix
  for (int i = tid; i < NF; i += 384) atomicAdd(&sm.s.hist[su[i] >> 4], 1u);
  __syncthreads();

  // suffix-scan over 4096 bins: thread t (t<256) owns bins [16t, 16t+16)
  uint pp = 0, suf = 0;
  if (tid < 256) {
#pragma unroll
    for (int j = 0; j < 16; ++j) pp += sm.s.hist[tid * 16 + j];
    suf = pp;
#pragma unroll
    for (int off = 1; off < 64; off <<= 1) {
      uint o = __shfl_down(suf, off);
      if (lane + off < 64) suf += o;
    }
    if (lane == 0) wtot[wvi] = suf;
  }
  __syncthreads();
  if (tid < 256) {
    uint later = 0;
    for (int wq = wvi + 1; wq < 4; ++wq) later += wtot[wq];
    uint geg = later + suf;        // sum of bins >= 16*tid
    uint gng = geg - pp;           // sum of bins >= 16*(tid+1)
    if (geg >= (uint)KSEL && gng < (uint)KSEL) {
      uint run = gng;
      int pv = 0;
      for (int j = 15; j >= 0; --j) {
        uint c = sm.s.hist[tid * 16 + j];
        uint nrun = run + c;
        if (nrun >= (uint)KSEL && run < (uint)KSEL) pv = tid * 16 + j;
        run = nrun;
      }
      sh_piv = (uint)pv;
    }
  }
  __syncthreads();
  uint piv = sh_piv;
  // collect all candidates with 12-bit prefix >= piv
  for (int i = tid; i < NF; i += 384) {
    uint u = su[i];
    if ((u >> 4) >= piv) {
      uint s = atomicAdd(&cnt, 1u);
      if (s < 1024) sm.s.cand[s] = (u << 13) | (8191u - (uint)i);
    }
  }
  __syncthreads();
  {
    uint m = cnt < 1024u ? cnt : 1024u;
    if (tid < (int)m) {
      uint me = sm.s.cand[tid];
      int r = 0;
      for (uint e = 0; e < m; ++e) r += (sm.s.cand[e] > me);
      if (r < KSEL) il[r] = 8191 - (int)(me & 8191u);
    }
  }
  __syncthreads();

  // exact fp32 rescore of the 48 candidates (8 threads per candidate)
  {
    int k = tid >> 3, j = tid & 7;
    const float* fp = x + ((size_t)b * STOT + T + il[k]) * C + j;
    float s = 0.f;
#pragma unroll 8
    for (int m2 = 0; m2 < 48; ++m2) s += fp[m2 * 8] * qS[j + m2 * 8];
    s += __shfl_down(s, 4);
    s += __shfl_down(s, 2);
    s += __shfl_down(s, 1);
    if (j == 0) sv[k] = s * SCALE;
  }
  __syncthreads();
  if (tid < KSEL) {
    float mys = sv[tid];
    int myn = il[tid];
    int r = 0;
#pragma unroll
    for (int e = 0; e < KSEL; ++e) {
      float se = sv[e];
      r += (se > mys) || (se == mys && il[e] < myn);
    }
    rkS[tid] = r;
    if (r == 0) smax = mys;
  }
  __syncthreads();
  {
    float e = 0.f;
    if (tid < KSEL && rkS[tid] < TOPK) e = expf(sv[tid] - smax);
    if (tid < 64) {
      float t2 = e;
#pragma unroll
      for (int off = 32; off; off >>= 1) t2 += __shfl_down(t2, off);
      if (tid == 0) esum = t2;
    }
    __syncthreads();
    if (tid < KSEL && rkS[tid] < TOPK) {
      wl[rkS[tid]] = e / esum;
      top_il[rkS[tid]] = il[tid];
    }
  }
  __syncthreads();  // selection LDS dead; union region reused below

  // ---- tail: fbar + g extraction (thread = column c) ----
  {
    float fbar = 0.f;
    bool ing = (tid >= hD) && (tid < hD + D);
#pragma unroll 4
    for (int k = 0; k < TOPK; ++k) {
      float v = x[((size_t)b * STOT + T + top_il[k]) * C + tid];
      float wv = wl[k] * v;
      fbar += wv;
      if (ing) sm.g.gS[k][tid - hD] = wv;
    }
    sm.g.fbarS[tid] = fbar;
  }
  __syncthreads();

  // att: 256 threads = 32 d x 8 segs of 48 c; Vw reads 128B-coalesced
  if (tid < 256) {
    int d = tid & 31, seg = tid >> 5;
    const float* vw = kv_w + C + hD + d;   // kv_w[c][C+hD+d], row stride 2C
    float a0 = 0.f, a1 = 0.f;
    int cb = seg * 48;
#pragma unroll 8
    for (int c = 0; c < 48; c += 2) {
      a0 += sm.g.fbarS[cb + c] * vw[(size_t)(cb + c) * (2 * C)];
      a1 += sm.g.fbarS[cb + c + 1] * vw[(size_t)(cb + c + 1) * (2 * C)];
    }
    sm.g.part[seg][d] = a0 + a1;
  }
  __syncthreads();
  if (tid < D) {
    float a = 0.f;
#pragma unroll
    for (int s = 0; s < 8; ++s) a += sm.g.part[s][tid];
    attS[tid] = a;
  }
  __syncthreads();

  // ---- scatter: thread = output column o = tid, 33 atomic rows ----
  float ewc[D];
  const float* ewt = ew + (size_t)t * C * C + (size_t)hD * C + tid;
#pragma unroll
  for (int dd = 0; dd < D; ++dd) ewc[dd] = ewt[(size_t)dd * C];
  size_t obase = (size_t)b * STOT * C + tid;
#pragma unroll 1
  for (int kk = 0; kk < TOPK; ++kk) {
    float y = 0.f;
#pragma unroll
    for (int d4 = 0; d4 < D; d4 += 4) {
      float4 g4 = *reinterpret_cast<const float4*>(&sm.g.gS[kk][d4]);
      y += g4.x * ewc[d4] + g4.y * ewc[d4 + 1] +
           g4.z * ewc[d4 + 2] + g4.w * ewc[d4 + 3];
    }
    atomicAdd(&out[obase + (size_t)(T + top_il[kk]) * C], y);
  }
  {
    float y = 0.f;
#pragma unroll
    for (int d4 = 0; d4 < D; d4 += 4) {
      float4 a4 = *reinterpret_cast<const float4*>(attS + d4);
      y += a4.x * ewc[d4] + a4.y * ewc[d4 + 1] +
           a4.z * ewc[d4 + 2] + a4.w * ewc[d4 + 3];
    }
    atomicAdd(&out[obase + (size_t)t * C], y);
  }
}

// ---------------------------------------------------------------------------
extern "C" void kernel_launch(void* const* d_in, const int* in_sizes, int n_in,
                              void* d_out, int out_size, void* d_ws, size_t ws_size,
                              hipStream_t stream) {
  const float* x = (const float*)d_in[0];
  const float* qs_w = (const float*)d_in[1];
  const float* kv_w = (const float*)d_in[2];
  const float* ew = (const float*)d_in[3];
  float* out = (float*)d_out;

  char* p = (char*)d_ws;
  float* qk_f32 = (float*)p;  p += (size_t)B * R * C * 4;        // 589824
  ushort* qk_bf = (ushort*)p; p += (size_t)B * R * C * 2;        // 294912
  ushort* keys = (ushort*)p;  p += (size_t)B * R * NF * 2;       // 6291456
  float* q_part = (float*)p;  // 2*B*T*C floats

  dim3 gq(T, C / 64, 2);
  ta_qproj_kernel<<<gq, 256, 0, stream>>>(x, qs_w, q_part);
  ta_fold_kernel<<<B * H, 384, 0, stream>>>(q_part, kv_w, qk_f32, qk_bf);
  dim3 g2(NF / 64, B);
  ta_scores_kernel<<<g2, 256, 0, stream>>>(x, qk_bf, keys, (float4*)out);
  ta_seltail_kernel<<<B * R, 384, 0, stream>>>(keys, x, qk_f32, kv_w, ew, out);
}